// Round 1
// 162.676 us; speedup vs baseline: 1.0800x; 1.0800x over previous
//
#include <hip/hip_runtime.h>

// PyramidToDepth: x (8,512,512,2) fp32 -> out (8,18,512,512,1) fp32
// levels lv=0..8, S=512>>lv; out[b, 2*lv+c, h, w] = bilinear_up(level_lv)[b,h,w,c]
//
// d_ws holds levels 1..6, channel-interleaved (B,S,S,2), float2-unit offsets:
//   lv:    1       2       3       4       5       6
//   off2:  0  524288  655360  688128  696320  698368
//
// Round theory: upsample was 16x 8B global gathers/thread (latency-bound read
// path in front of the 151MB write stream). Now: block stages its <=3 source
// rows into LDS (coalesced), gathers from LDS. lv0 identity output fused into
// build (x already in registers there) -> x read once, one fewer z-slice.

#define HWTOT (512 * 512)

typedef float vfloat4 __attribute__((ext_vector_type(4)));

__constant__ int c_off2[7] = {0, 0, 524288, 655360, 688128, 696320, 698368};

// --- Kernel A: levels 1..6 + lv0 identity planes. One block per 64x64 tile. --
__global__ __launch_bounds__(256) void build_levels_1_6(const float* __restrict__ x,
                                                        float2* __restrict__ pyr,
                                                        float* __restrict__ out) {
  const int b = blockIdx.y;
  const int tx = blockIdx.x & 7, ty = blockIdx.x >> 3;
  const int t = threadIdx.x;

  __shared__ float2 sh1[32 * 32];
  __shared__ float2 sh2[16 * 16];
  __shared__ float2 sh3[8 * 8];
  __shared__ float2 sh4[4 * 4];
  __shared__ float2 sh5[2 * 2];

  // level 1: 32x32 tile-local, 4 consecutive cols per thread. Also emit lv0.
  {
    const int i = t >> 3;
    const int j0 = (t & 7) << 2;
    const int row0 = ty * 64 + 2 * i;      // x row (even)
    const int colx = tx * 64 + 2 * j0;     // x pixel col base (8 pixels)
    const float* r0 = x + (((size_t)(b * 512 + row0)) * 512 + colx) * 2;
    const float* r1 = r0 + 1024;
    float4 a[4], c[4];
    float2 o[4];
#pragma unroll
    for (int k = 0; k < 4; ++k) {
      a[k] = *(const float4*)(r0 + 4 * k);
      c[k] = *(const float4*)(r1 + 4 * k);
      o[k].x = (a[k].x + a[k].z + c[k].x + c[k].z) * 0.25f;
      o[k].y = (a[k].y + a[k].w + c[k].y + c[k].w) * 0.25f;
      sh1[i * 32 + j0 + k] = o[k];
    }
    float2* g = pyr + ((size_t)(b * 256 + ty * 32 + i) * 256 + tx * 32 + j0);
    *(float4*)(g) = make_float4(o[0].x, o[0].y, o[1].x, o[1].y);
    *(float4*)(g + 2) = make_float4(o[2].x, o[2].y, o[3].x, o[3].y);

    // lv0 identity resize: channels 0 (x) and 1 (y), rows row0 and row0+1.
    const size_t ob = (size_t)(b * 18) * HWTOT + (size_t)row0 * 512 + colx;
    *(vfloat4*)(out + ob)                  = (vfloat4){a[0].x, a[0].z, a[1].x, a[1].z};
    *(vfloat4*)(out + ob + 4)              = (vfloat4){a[2].x, a[2].z, a[3].x, a[3].z};
    *(vfloat4*)(out + ob + 512)            = (vfloat4){c[0].x, c[0].z, c[1].x, c[1].z};
    *(vfloat4*)(out + ob + 512 + 4)        = (vfloat4){c[2].x, c[2].z, c[3].x, c[3].z};
    *(vfloat4*)(out + ob + HWTOT)          = (vfloat4){a[0].y, a[0].w, a[1].y, a[1].w};
    *(vfloat4*)(out + ob + HWTOT + 4)      = (vfloat4){a[2].y, a[2].w, a[3].y, a[3].w};
    *(vfloat4*)(out + ob + HWTOT + 512)    = (vfloat4){c[0].y, c[0].w, c[1].y, c[1].w};
    *(vfloat4*)(out + ob + HWTOT + 512 + 4)= (vfloat4){c[2].y, c[2].w, c[3].y, c[3].w};
  }
  __syncthreads();
  // level 2: 16x16
  {
    const int i = t >> 4, j = t & 15;
    float2 a = sh1[(2 * i) * 32 + 2 * j], c = sh1[(2 * i) * 32 + 2 * j + 1];
    float2 d = sh1[(2 * i + 1) * 32 + 2 * j], e = sh1[(2 * i + 1) * 32 + 2 * j + 1];
    float2 o = {(a.x + c.x + d.x + e.x) * 0.25f, (a.y + c.y + d.y + e.y) * 0.25f};
    sh2[i * 16 + j] = o;
    pyr[524288 + (size_t)(b * 128 + ty * 16 + i) * 128 + tx * 16 + j] = o;
  }
  __syncthreads();
  // level 3: 8x8
  if (t < 64) {
    const int i = t >> 3, j = t & 7;
    float2 a = sh2[(2 * i) * 16 + 2 * j], c = sh2[(2 * i) * 16 + 2 * j + 1];
    float2 d = sh2[(2 * i + 1) * 16 + 2 * j], e = sh2[(2 * i + 1) * 16 + 2 * j + 1];
    float2 o = {(a.x + c.x + d.x + e.x) * 0.25f, (a.y + c.y + d.y + e.y) * 0.25f};
    sh3[i * 8 + j] = o;
    pyr[655360 + (size_t)(b * 64 + ty * 8 + i) * 64 + tx * 8 + j] = o;
  }
  __syncthreads();
  // level 4: 4x4
  if (t < 16) {
    const int i = t >> 2, j = t & 3;
    float2 a = sh3[(2 * i) * 8 + 2 * j], c = sh3[(2 * i) * 8 + 2 * j + 1];
    float2 d = sh3[(2 * i + 1) * 8 + 2 * j], e = sh3[(2 * i + 1) * 8 + 2 * j + 1];
    float2 o = {(a.x + c.x + d.x + e.x) * 0.25f, (a.y + c.y + d.y + e.y) * 0.25f};
    sh4[i * 4 + j] = o;
    pyr[688128 + (size_t)(b * 32 + ty * 4 + i) * 32 + tx * 4 + j] = o;
  }
  __syncthreads();
  // level 5: 2x2
  if (t < 4) {
    const int i = t >> 1, j = t & 1;
    float2 a = sh4[(2 * i) * 4 + 2 * j], c = sh4[(2 * i) * 4 + 2 * j + 1];
    float2 d = sh4[(2 * i + 1) * 4 + 2 * j], e = sh4[(2 * i + 1) * 4 + 2 * j + 1];
    float2 o = {(a.x + c.x + d.x + e.x) * 0.25f, (a.y + c.y + d.y + e.y) * 0.25f};
    sh5[i * 2 + j] = o;
    pyr[696320 + (size_t)(b * 16 + ty * 2 + i) * 16 + tx * 2 + j] = o;
  }
  __syncthreads();
  // level 6: 1x1
  if (t == 0) {
    float2 a = sh5[0], c = sh5[1], d = sh5[2], e = sh5[3];
    float2 o = {(a.x + c.x + d.x + e.x) * 0.25f, (a.y + c.y + d.y + e.y) * 0.25f};
    pyr[698368 + (size_t)(b * 8 + ty) * 8 + tx] = o;
  }
}

// --- Kernel B: levels 1..8, one LEVEL per block (blockIdx.z = lv-1). ---------
// Block covers output rows {2*bx, 2*bx+1} x all 512 cols for one (b, lv).
// lv<=6: stage the 3 needed source rows (clamped) into LDS, gather from LDS.
// lv 7/8: rebuild the tiny image in LDS from lv6 (same rounding chain), then
// the same unified LDS gather loop.
__global__ __launch_bounds__(256) void upsample_lv(const float2* __restrict__ pyr,
                                                   float* __restrict__ out) {
  const int t = threadIdx.x;
  const int w0pix = (t & 127) << 2;            // 4 consecutive w
  const int dr = t >> 7;                       // 0 or 1 (wave-uniform)
  const int h = (blockIdx.x << 1) + dr;
  const int b = blockIdx.y;
  const int lv = blockIdx.z + 1;               // 1..8, block-uniform
  const size_t obase = (size_t)(b * 18 + 2 * lv) * HWTOT + (size_t)h * 512 + w0pix;

  // lv<=6: rows[0..3S) = 3 staged rows. lv7: rows[0..15] = 4x4. lv8: rows[16..19] = 2x2.
  __shared__ float2 rows[3 * 256];

  const int S = 512 >> lv;
  const float scale = 1.0f / (float)(1 << lv);

  int ldsR0, ldsR1;  // float2 index of interp rows in LDS
  float fh;

  if (lv <= 6) {
    // lowest source row any output row of this block can touch:
    //   hbase = floor((2*bx + 0.5)*scale - 0.5);  needed rows ⊆ {hbase..hbase+2}
    const float hb_e = ((float)(blockIdx.x << 1) + 0.5f) * scale - 0.5f;
    const int hbase = (int)floorf(hb_e);
    const int shl = 9 - lv;  // log2(S)
    for (int idx = t; idx < 3 * S; idx += 256) {
      int r = idx >> shl;
      int wc = idx & (S - 1);
      int sr = hbase + r;
      sr = sr < 0 ? 0 : (sr > S - 1 ? S - 1 : sr);
      rows[idx] = pyr[c_off2[lv] + (size_t)b * S * S + (size_t)sr * S + wc];
    }
    __syncthreads();
    const float sh = ((float)h + 0.5f) * scale - 0.5f;
    const float f0 = floorf(sh);
    fh = sh - f0;
    const int d0 = (int)f0 - hbase;  // 0 or 1; clamping is baked into staging
    ldsR0 = d0 * S;
    ldsR1 = ldsR0 + S;
  } else {
    // rebuild lv7 (and lv8) from lv6 in LDS; block-uniform branches -> sync safe
    const float2* l6 = pyr + 698368 + (size_t)b * 64;
    if (t < 16) {
      const int i = t >> 2, j = t & 3;
      float2 a = l6[(2 * i) * 8 + 2 * j], c = l6[(2 * i) * 8 + 2 * j + 1];
      float2 d = l6[(2 * i + 1) * 8 + 2 * j], e = l6[(2 * i + 1) * 8 + 2 * j + 1];
      rows[t] = {(a.x + c.x + d.x + e.x) * 0.25f, (a.y + c.y + d.y + e.y) * 0.25f};
    }
    __syncthreads();
    if (lv == 8) {
      if (t < 4) {
        const int i = t >> 1, j = t & 1;
        float2 a = rows[(2 * i) * 4 + 2 * j], c = rows[(2 * i) * 4 + 2 * j + 1];
        float2 d = rows[(2 * i + 1) * 4 + 2 * j], e = rows[(2 * i + 1) * 4 + 2 * j + 1];
        rows[16 + t] = {(a.x + c.x + d.x + e.x) * 0.25f, (a.y + c.y + d.y + e.y) * 0.25f};
      }
      __syncthreads();
    }
    const int off = (lv == 7) ? 0 : 16;
    const float sh = ((float)h + 0.5f) * scale - 0.5f;
    const float f0 = floorf(sh);
    fh = sh - f0;
    int h0 = (int)f0;
    int h0c = h0 < 0 ? 0 : h0;
    int h1c = (h0 + 1 > S - 1) ? (S - 1) : (h0 + 1);
    ldsR0 = off + h0c * S;
    ldsR1 = off + h1c * S;
  }

  // jax.image.resize bilinear = half-pixel centers + clamp-to-edge
  const float wy0 = 1.0f - fh;
  float o0[4], o1[4];
#pragma unroll
  for (int k = 0; k < 4; ++k) {
    float sw = ((float)(w0pix + k) + 0.5f) * scale - 0.5f;
    float fw0f = floorf(sw);
    float fw = sw - fw0f;
    int w0 = (int)fw0f;
    int w0c = w0 < 0 ? 0 : w0;
    int w1c = (w0 + 1 > S - 1) ? (S - 1) : (w0 + 1);
    float2 v00 = rows[ldsR0 + w0c], v01 = rows[ldsR0 + w1c];
    float2 v10 = rows[ldsR1 + w0c], v11 = rows[ldsR1 + w1c];
    float wx0 = 1.0f - fw;
    float tx_ = v00.x * wx0 + v01.x * fw;
    float bx_ = v10.x * wx0 + v11.x * fw;
    float ty_ = v00.y * wx0 + v01.y * fw;
    float by_ = v10.y * wx0 + v11.y * fw;
    o0[k] = tx_ * wy0 + bx_ * fh;
    o1[k] = ty_ * wy0 + by_ * fh;
  }
  *(vfloat4*)(out + obase) = (vfloat4){o0[0], o0[1], o0[2], o0[3]};
  *(vfloat4*)(out + obase + HWTOT) = (vfloat4){o1[0], o1[1], o1[2], o1[3]};
}

extern "C" void kernel_launch(void* const* d_in, const int* in_sizes, int n_in,
                              void* d_out, int out_size, void* d_ws, size_t ws_size,
                              hipStream_t stream) {
  const float* x = (const float*)d_in[0];
  float* out = (float*)d_out;
  float2* pyr = (float2*)d_ws;

  build_levels_1_6<<<dim3(64, 8), 256, 0, stream>>>(x, pyr, out);
  upsample_lv<<<dim3(256, 8, 8), 256, 0, stream>>>(pyr, out);
}